// Round 1
// baseline (770.004 us; speedup 1.0000x reference)
//
#include <hip/hip_runtime.h>
#include <math.h>

constexpr int DIN = 128;

// ---------------- CSR build ----------------

__global__ __launch_bounds__(256) void histo_kernel(const int* __restrict__ ei,
                                                    int* __restrict__ deg, int E, int n) {
  int k = blockIdx.x * 256 + threadIdx.x;
  if (k >= E + n) return;
  int dst = (k < E) ? ei[E + k] : (k - E);   // self-loop edges appended
  atomicAdd(&deg[dst], 1);
}

__global__ __launch_bounds__(1024) void scan_kernel(const int* __restrict__ deg,
                                                    int* __restrict__ row_ptr, int n) {
  __shared__ int buf[1024];
  __shared__ int carry;
  const int tid = threadIdx.x;
  if (tid == 0) carry = 0;
  __syncthreads();
  for (int base = 0; base < n; base += 1024) {
    int i = base + tid;
    int v = (i < n) ? deg[i] : 0;
    buf[tid] = v;
    __syncthreads();
    for (int off = 1; off < 1024; off <<= 1) {
      int t = (tid >= off) ? buf[tid - off] : 0;
      __syncthreads();
      buf[tid] += t;
      __syncthreads();
    }
    int incl = buf[tid];
    int c = carry;
    int total = buf[1023];
    __syncthreads();
    if (i < n) row_ptr[i] = c + incl - v;   // exclusive scan
    if (tid == 0) carry = c + total;
    __syncthreads();
  }
  if (tid == 0) row_ptr[n] = carry;
}

__global__ __launch_bounds__(256) void scatter_kernel(const int* __restrict__ ei,
    const int* __restrict__ row_ptr, int* __restrict__ fill,
    int* __restrict__ edge_src, int E, int n) {
  int k = blockIdx.x * 256 + threadIdx.x;
  if (k >= E + n) return;
  int src, dst;
  if (k < E) { src = ei[k]; dst = ei[E + k]; }
  else       { src = k - E; dst = k - E; }
  int pos = row_ptr[dst] + atomicAdd(&fill[dst], 1);
  edge_src[pos] = src;
}

// ---------------- dual GEMM: outl = A@Wl, outr = A@Wr  (K=128 fixed) ----------------

template<int NC>
__global__ __launch_bounds__(256) void gemm2_kernel(const float* __restrict__ A,
    const float* __restrict__ Wl, const float* __restrict__ Wr,
    float* __restrict__ outl, float* __restrict__ outr, int M) {
  constexpr int K  = 128;
  constexpr int BR = 64;   // rows per block
  constexpr int KT = 64;   // k-tile for W staging
  __shared__ float As[BR][K];        // 32 KB
  __shared__ float Ws[KT][NC];       // 32 KB (NC=128) / 16 KB (NC=64)
  const int tid  = threadIdx.x;
  const int row0 = blockIdx.x * BR;

  // stage A tile (zero-padded past M)
  for (int idx = tid * 4; idx < BR * K; idx += 1024) {
    int r = idx >> 7, cc = idx & 127;
    float4 v;
    if (row0 + r < M) v = *(const float4*)&A[(size_t)(row0 + r) * K + cc];
    else              v = make_float4(0.f, 0.f, 0.f, 0.f);
    *(float4*)&As[r][cc] = v;
  }

  constexpr int CG  = NC / 4;      // col groups (4 cols each)
  constexpr int RG  = 256 / CG;    // row groups
  constexpr int RPT = BR / RG;     // rows per thread
  const int c     = (tid % CG) * 4;
  const int rbase = (tid / CG) * RPT;

  const float* W = Wl;
  float* outp = outl;
  for (int pass = 0; pass < 2; ++pass) {
    float acc[RPT][4] = {};
    for (int kt = 0; kt < K; kt += KT) {
      __syncthreads();   // covers A staging (first iter) / prior compute on Ws
      for (int idx = tid * 4; idx < KT * NC; idx += 1024) {
        int kk = idx / NC, cc = idx % NC;
        *(float4*)&Ws[kk][cc] = *(const float4*)&W[(size_t)(kt + kk) * NC + cc];
      }
      __syncthreads();
#pragma unroll 8
      for (int k = 0; k < KT; ++k) {
        float4 w = *(const float4*)&Ws[k][c];
#pragma unroll
        for (int i = 0; i < RPT; ++i) {
          float a = As[rbase + i][kt + k];
          acc[i][0] = fmaf(a, w.x, acc[i][0]);
          acc[i][1] = fmaf(a, w.y, acc[i][1]);
          acc[i][2] = fmaf(a, w.z, acc[i][2]);
          acc[i][3] = fmaf(a, w.w, acc[i][3]);
        }
      }
    }
    for (int i = 0; i < RPT; ++i) {
      int r = row0 + rbase + i;
      if (r < M)
        *(float4*)&outp[(size_t)r * NC + c] =
            make_float4(acc[i][0], acc[i][1], acc[i][2], acc[i][3]);
    }
    W = Wr; outp = outr;
  }
}

// ---------------- per-node online-softmax aggregation ----------------
// layers 1-2: 128 channels (4 heads x 32), one wave per node, lane holds c and c+64.

__global__ __launch_bounds__(256) void aggregate128_kernel(
    const float* __restrict__ xl, const float* __restrict__ xr,
    const float* __restrict__ att, const float* __restrict__ bias,
    const int* __restrict__ row_ptr, const int* __restrict__ edge_src,
    float* __restrict__ out, int n) {
  int node = (blockIdx.x * 256 + threadIdx.x) >> 6;
  int lane = threadIdx.x & 63;
  if (node >= n) return;
  const int c0 = lane, c1 = lane + 64;
  const float xr0 = xr[(size_t)node * 128 + c0];
  const float xr1 = xr[(size_t)node * 128 + c1];
  const float a0 = att[c0], a1 = att[c1];
  float m0 = -INFINITY, m1 = -INFINITY;
  float l0 = 0.f, l1 = 0.f, o0 = 0.f, o1 = 0.f;
  const int beg = row_ptr[node], end = row_ptr[node + 1];
  for (int idx = beg; idx < end; ++idx) {
    int s = edge_src[idx];
    float xl0 = xl[(size_t)s * 128 + c0];
    float xl1 = xl[(size_t)s * 128 + c1];
    float t0 = xl0 + xr0, t1 = xl1 + xr1;
    float p0 = (t0 > 0.f ? t0 : 0.2f * t0) * a0;
    float p1 = (t1 > 0.f ? t1 : 0.2f * t1) * a1;
#pragma unroll
    for (int off = 16; off >= 1; off >>= 1) {   // reduce over each 32-lane half = one head
      p0 += __shfl_xor(p0, off, 64);
      p1 += __shfl_xor(p1, off, 64);
    }
    // p0/p1 are now e[head(c0)], e[head(c1)] (identical across each half-wave)
    float nm0 = fmaxf(m0, p0), nm1 = fmaxf(m1, p1);
    float s0 = __expf(m0 - nm0), s1 = __expf(m1 - nm1);  // first iter: exp(-inf)=0
    float ex0 = __expf(p0 - nm0), ex1 = __expf(p1 - nm1);
    l0 = l0 * s0 + ex0;        l1 = l1 * s1 + ex1;
    o0 = o0 * s0 + ex0 * xl0;  o1 = o1 * s1 + ex1 * xl1;
    m0 = nm0; m1 = nm1;
  }
  float r0 = o0 / l0 + bias[c0];
  float r1 = o1 / l1 + bias[c1];
  // ELU (alpha=1)
  r0 = r0 > 0.f ? r0 : __expf(r0) - 1.f;
  r1 = r1 > 0.f ? r1 : __expf(r1) - 1.f;
  out[(size_t)node * 128 + c0] = r0;
  out[(size_t)node * 128 + c1] = r1;
}

// layer 3: 64 channels (4 heads x 16), fused log_softmax over the 64 outputs.

__global__ __launch_bounds__(256) void aggregate64_kernel(
    const float* __restrict__ xl, const float* __restrict__ xr,
    const float* __restrict__ att, const float* __restrict__ bias,
    const int* __restrict__ row_ptr, const int* __restrict__ edge_src,
    float* __restrict__ out, int n) {
  int node = (blockIdx.x * 256 + threadIdx.x) >> 6;
  int lane = threadIdx.x & 63;
  if (node >= n) return;
  const int c = lane;                      // head = c/16
  const float xrc = xr[(size_t)node * 64 + c];
  const float a = att[c];
  float m = -INFINITY, l = 0.f, o = 0.f;
  const int beg = row_ptr[node], end = row_ptr[node + 1];
  for (int idx = beg; idx < end; ++idx) {
    int s = edge_src[idx];
    float xlc = xl[(size_t)s * 64 + c];
    float t = xlc + xrc;
    float p = (t > 0.f ? t : 0.2f * t) * a;
#pragma unroll
    for (int off = 8; off >= 1; off >>= 1)   // reduce over each 16-lane group = one head
      p += __shfl_xor(p, off, 64);
    float nm = fmaxf(m, p);
    float sc = __expf(m - nm);
    float ex = __expf(p - nm);
    l = l * sc + ex;
    o = o * sc + ex * xlc;
    m = nm;
  }
  float r = o / l + bias[c];
  // log_softmax across all 64 lanes (= the node's 64 outputs)
  float mx = r;
#pragma unroll
  for (int off = 32; off >= 1; off >>= 1) mx = fmaxf(mx, __shfl_xor(mx, off, 64));
  float ex = __expf(r - mx);
  float se = ex;
#pragma unroll
  for (int off = 32; off >= 1; off >>= 1) se += __shfl_xor(se, off, 64);
  out[(size_t)node * 64 + c] = r - mx - __logf(se);
}

// ---------------- launcher ----------------

extern "C" void kernel_launch(void* const* d_in, const int* in_sizes, int n_in,
                              void* d_out, int out_size, void* d_ws, size_t ws_size,
                              hipStream_t stream) {
  const float* x    = (const float*)d_in[0];
  const int*   ei   = (const int*)d_in[1];
  const float* Wl1  = (const float*)d_in[2];
  const float* Wr1  = (const float*)d_in[3];
  const float* att1 = (const float*)d_in[4];
  const float* b1   = (const float*)d_in[5];
  const float* Wl2  = (const float*)d_in[6];
  const float* Wr2  = (const float*)d_in[7];
  const float* att2 = (const float*)d_in[8];
  const float* b2   = (const float*)d_in[9];
  const float* Wl3  = (const float*)d_in[10];
  const float* Wr3  = (const float*)d_in[11];
  const float* att3 = (const float*)d_in[12];
  const float* b3   = (const float*)d_in[13];
  const int n = in_sizes[0] / DIN;    // 50000
  const int E = in_sizes[1] / 2;      // 800000
  float* out = (float*)d_out;

  float* xl = (float*)d_ws;                      // n*128
  float* xr = xl + (size_t)n * 128;              // n*128
  float* h  = xr + (size_t)n * 128;              // n*128
  int* row_ptr  = (int*)(h + (size_t)n * 128);   // n+1
  int* fill     = row_ptr + (n + 1);             // n (doubles as degree array)
  int* edge_src = fill + n;                      // E+n

  const int tot = E + n;
  const int tb = (tot + 255) / 256;
  hipMemsetAsync(fill, 0, (size_t)n * sizeof(int), stream);
  histo_kernel<<<tb, 256, 0, stream>>>(ei, fill, E, n);
  scan_kernel<<<1, 1024, 0, stream>>>(fill, row_ptr, n);
  hipMemsetAsync(fill, 0, (size_t)n * sizeof(int), stream);
  scatter_kernel<<<tb, 256, 0, stream>>>(ei, row_ptr, fill, edge_src, E, n);

  const int gb = (n + 63) / 64;   // gemm blocks
  const int ab = (n + 3) / 4;     // aggregate blocks (4 waves/block)

  // layer 1
  gemm2_kernel<128><<<gb, 256, 0, stream>>>(x, Wl1, Wr1, xl, xr, n);
  aggregate128_kernel<<<ab, 256, 0, stream>>>(xl, xr, att1, b1, row_ptr, edge_src, h, n);
  // layer 2
  gemm2_kernel<128><<<gb, 256, 0, stream>>>(h, Wl2, Wr2, xl, xr, n);
  aggregate128_kernel<<<ab, 256, 0, stream>>>(xl, xr, att2, b2, row_ptr, edge_src, h, n);
  // layer 3
  gemm2_kernel<64><<<gb, 256, 0, stream>>>(h, Wl3, Wr3, xl, xr, n);
  aggregate64_kernel<<<ab, 256, 0, stream>>>(xl, xr, att3, b3, row_ptr, edge_src, out, n);
}

// Round 2
// 586.700 us; speedup vs baseline: 1.3124x; 1.3124x over previous
//
#include <hip/hip_runtime.h>
#include <math.h>

constexpr int DIN = 128;

// ---------------- CSR build ----------------

__global__ __launch_bounds__(256) void histo_kernel(const int* __restrict__ ei,
                                                    int* __restrict__ deg, int E, int n) {
  int k = blockIdx.x * 256 + threadIdx.x;
  if (k >= E + n) return;
  int dst = (k < E) ? ei[E + k] : (k - E);   // self-loop edges appended
  atomicAdd(&deg[dst], 1);
}

// single-block scan, wave-shfl based (2 barriers per 1024-chunk instead of 20)
__global__ __launch_bounds__(1024) void scan_kernel(const int* __restrict__ deg,
                                                    int* __restrict__ row_ptr, int n) {
  __shared__ int wsum[16];
  __shared__ int carry;
  const int tid  = threadIdx.x;
  const int lane = tid & 63;
  const int wid  = tid >> 6;
  if (tid == 0) carry = 0;
  __syncthreads();
  for (int base = 0; base < n; base += 1024) {
    int i = base + tid;
    int v = (i < n) ? deg[i] : 0;
    int incl = v;
#pragma unroll
    for (int off = 1; off < 64; off <<= 1) {
      int t = __shfl_up(incl, off, 64);
      if (lane >= off) incl += t;
    }
    if (lane == 63) wsum[wid] = incl;
    __syncthreads();
    if (wid == 0) {
      int wv = (lane < 16) ? wsum[lane] : 0;
#pragma unroll
      for (int off = 1; off < 16; off <<= 1) {
        int t = __shfl_up(wv, off, 64);
        if (lane >= off) wv += t;
      }
      if (lane < 16) wsum[lane] = wv;
    }
    __syncthreads();
    int woff  = (wid == 0) ? 0 : wsum[wid - 1];
    int c     = carry;
    int total = wsum[15];
    __syncthreads();
    if (i < n) row_ptr[i] = c + woff + incl - v;   // exclusive scan
    if (tid == 0) carry = c + total;
    __syncthreads();
  }
  if (tid == 0) row_ptr[n] = carry;
}

__global__ __launch_bounds__(256) void scatter_kernel(const int* __restrict__ ei,
    const int* __restrict__ row_ptr, int* __restrict__ fill,
    int* __restrict__ edge_src, int E, int n) {
  int k = blockIdx.x * 256 + threadIdx.x;
  if (k >= E + n) return;
  int src, dst;
  if (k < E) { src = ei[k]; dst = ei[E + k]; }
  else       { src = k - E; dst = k - E; }
  int pos = row_ptr[dst] + atomicAdd(&fill[dst], 1);
  edge_src[pos] = src;
}

// ---------------- dual GEMM: outl = A@Wl, outr = A@Wr  (K=128 fixed) ----------------

template<int NC>
__global__ __launch_bounds__(256) void gemm2_kernel(const float* __restrict__ A,
    const float* __restrict__ Wl, const float* __restrict__ Wr,
    float* __restrict__ outl, float* __restrict__ outr, int M) {
  constexpr int K  = 128;
  constexpr int BR = 64;   // rows per block
  constexpr int KT = 64;   // k-tile for W staging
  __shared__ float As[BR][K];        // 32 KB
  __shared__ float Ws[KT][NC];       // 32 KB (NC=128) / 16 KB (NC=64)
  const int tid  = threadIdx.x;
  const int row0 = blockIdx.x * BR;

  // stage A tile (zero-padded past M)
  for (int idx = tid * 4; idx < BR * K; idx += 1024) {
    int r = idx >> 7, cc = idx & 127;
    float4 v;
    if (row0 + r < M) v = *(const float4*)&A[(size_t)(row0 + r) * K + cc];
    else              v = make_float4(0.f, 0.f, 0.f, 0.f);
    *(float4*)&As[r][cc] = v;
  }

  constexpr int CG  = NC / 4;      // col groups (4 cols each)
  constexpr int RG  = 256 / CG;    // row groups
  constexpr int RPT = BR / RG;     // rows per thread
  const int c     = (tid % CG) * 4;
  const int rbase = (tid / CG) * RPT;

  const float* W = Wl;
  float* outp = outl;
  for (int pass = 0; pass < 2; ++pass) {
    float acc[RPT][4] = {};
    for (int kt = 0; kt < K; kt += KT) {
      __syncthreads();   // covers A staging (first iter) / prior compute on Ws
      for (int idx = tid * 4; idx < KT * NC; idx += 1024) {
        int kk = idx / NC, cc = idx % NC;
        *(float4*)&Ws[kk][cc] = *(const float4*)&W[(size_t)(kt + kk) * NC + cc];
      }
      __syncthreads();
#pragma unroll 4
      for (int k = 0; k < KT; k += 4) {
        float4 w0 = *(const float4*)&Ws[k + 0][c];
        float4 w1 = *(const float4*)&Ws[k + 1][c];
        float4 w2 = *(const float4*)&Ws[k + 2][c];
        float4 w3 = *(const float4*)&Ws[k + 3][c];
#pragma unroll
        for (int i = 0; i < RPT; ++i) {
          float4 a = *(const float4*)&As[rbase + i][kt + k];
          acc[i][0] = fmaf(a.x, w0.x, acc[i][0]);
          acc[i][1] = fmaf(a.x, w0.y, acc[i][1]);
          acc[i][2] = fmaf(a.x, w0.z, acc[i][2]);
          acc[i][3] = fmaf(a.x, w0.w, acc[i][3]);
          acc[i][0] = fmaf(a.y, w1.x, acc[i][0]);
          acc[i][1] = fmaf(a.y, w1.y, acc[i][1]);
          acc[i][2] = fmaf(a.y, w1.z, acc[i][2]);
          acc[i][3] = fmaf(a.y, w1.w, acc[i][3]);
          acc[i][0] = fmaf(a.z, w2.x, acc[i][0]);
          acc[i][1] = fmaf(a.z, w2.y, acc[i][1]);
          acc[i][2] = fmaf(a.z, w2.z, acc[i][2]);
          acc[i][3] = fmaf(a.z, w2.w, acc[i][3]);
          acc[i][0] = fmaf(a.w, w3.x, acc[i][0]);
          acc[i][1] = fmaf(a.w, w3.y, acc[i][1]);
          acc[i][2] = fmaf(a.w, w3.z, acc[i][2]);
          acc[i][3] = fmaf(a.w, w3.w, acc[i][3]);
        }
      }
    }
    for (int i = 0; i < RPT; ++i) {
      int r = row0 + rbase + i;
      if (r < M)
        *(float4*)&outp[(size_t)r * NC + c] =
            make_float4(acc[i][0], acc[i][1], acc[i][2], acc[i][3]);
    }
    W = Wr; outp = outr;
  }
}

// ---------------- per-node online-softmax aggregation ----------------
// layers 1-2: 128 channels (4 heads x 32). One wave per node; lane holds
// channels 2*lane, 2*lane+1 (same head) -> head = 16-lane group, one 4-shfl
// reduce per edge. Edges unrolled x4 with a single combined rescale.

__global__ __launch_bounds__(256) void aggregate128_kernel(
    const float* __restrict__ xl, const float* __restrict__ xr,
    const float* __restrict__ att, const float* __restrict__ bias,
    const int* __restrict__ row_ptr, const int* __restrict__ edge_src,
    float* __restrict__ out, int n) {
  int node = (blockIdx.x * 256 + threadIdx.x) >> 6;
  int lane = threadIdx.x & 63;
  if (node >= n) return;
  const int c = lane * 2;
  const float2 xrv = *(const float2*)&xr[(size_t)node * 128 + c];
  const float2 av  = *(const float2*)&att[c];
  float m = -INFINITY, l = 0.f, o0 = 0.f, o1 = 0.f;
  const int beg = row_ptr[node], end = row_ptr[node + 1];
  int idx = beg;

#define SCORE128(S, XV, P)                                        \
  {                                                               \
    XV = *(const float2*)&xl[(size_t)(S) * 128 + c];              \
    float t0 = XV.x + xrv.x, t1 = XV.y + xrv.y;                   \
    t0 = t0 > 0.f ? t0 : 0.2f * t0;                               \
    t1 = t1 > 0.f ? t1 : 0.2f * t1;                               \
    P = t0 * av.x + t1 * av.y;                                    \
    P += __shfl_xor(P, 1, 64);                                    \
    P += __shfl_xor(P, 2, 64);                                    \
    P += __shfl_xor(P, 4, 64);                                    \
    P += __shfl_xor(P, 8, 64);                                    \
  }

  for (; idx + 4 <= end; idx += 4) {
    int sa = edge_src[idx], sb = edge_src[idx + 1];
    int sc_ = edge_src[idx + 2], sd = edge_src[idx + 3];
    float2 xa, xb, xc, xd;
    float pa, pb, pc, pd;
    SCORE128(sa, xa, pa);
    SCORE128(sb, xb, pb);
    SCORE128(sc_, xc, pc);
    SCORE128(sd, xd, pd);
    float nm = fmaxf(m, fmaxf(fmaxf(pa, pb), fmaxf(pc, pd)));
    float sc = __expf(m - nm);
    float ea = __expf(pa - nm), eb = __expf(pb - nm);
    float ec = __expf(pc - nm), ed = __expf(pd - nm);
    l  = fmaf(l, sc, (ea + eb) + (ec + ed));
    o0 = fmaf(o0, sc, (ea * xa.x + eb * xb.x) + (ec * xc.x + ed * xd.x));
    o1 = fmaf(o1, sc, (ea * xa.y + eb * xb.y) + (ec * xc.y + ed * xd.y));
    m = nm;
  }
  for (; idx < end; ++idx) {
    int s = edge_src[idx];
    float2 xv; float p;
    SCORE128(s, xv, p);
    float nm = fmaxf(m, p);
    float sc = __expf(m - nm);
    float e  = __expf(p - nm);
    l  = fmaf(l, sc, e);
    o0 = fmaf(o0, sc, e * xv.x);
    o1 = fmaf(o1, sc, e * xv.y);
    m = nm;
  }
#undef SCORE128

  const float2 bv = *(const float2*)&bias[c];
  float r0 = o0 / l + bv.x;
  float r1 = o1 / l + bv.y;
  // ELU (alpha=1)
  r0 = r0 > 0.f ? r0 : __expf(r0) - 1.f;
  r1 = r1 > 0.f ? r1 : __expf(r1) - 1.f;
  *(float2*)&out[(size_t)node * 128 + c] = make_float2(r0, r1);
}

// layer 3: 64 channels (4 heads x 16), fused log_softmax over the 64 outputs.

__global__ __launch_bounds__(256) void aggregate64_kernel(
    const float* __restrict__ xl, const float* __restrict__ xr,
    const float* __restrict__ att, const float* __restrict__ bias,
    const int* __restrict__ row_ptr, const int* __restrict__ edge_src,
    float* __restrict__ out, int n) {
  int node = (blockIdx.x * 256 + threadIdx.x) >> 6;
  int lane = threadIdx.x & 63;
  if (node >= n) return;
  const int c = lane;                      // head = c/16
  const float xrc = xr[(size_t)node * 64 + c];
  const float a = att[c];
  float m = -INFINITY, l = 0.f, o = 0.f;
  const int beg = row_ptr[node], end = row_ptr[node + 1];
  int idx = beg;

#define SCORE64(S, XV, P)                                         \
  {                                                               \
    XV = xl[(size_t)(S) * 64 + c];                                \
    float t = XV + xrc;                                           \
    t = t > 0.f ? t : 0.2f * t;                                   \
    P = t * a;                                                    \
    P += __shfl_xor(P, 1, 64);                                    \
    P += __shfl_xor(P, 2, 64);                                    \
    P += __shfl_xor(P, 4, 64);                                    \
    P += __shfl_xor(P, 8, 64);                                    \
  }

  for (; idx + 4 <= end; idx += 4) {
    int sa = edge_src[idx], sb = edge_src[idx + 1];
    int sc_ = edge_src[idx + 2], sd = edge_src[idx + 3];
    float xa, xb, xc, xd, pa, pb, pc, pd;
    SCORE64(sa, xa, pa);
    SCORE64(sb, xb, pb);
    SCORE64(sc_, xc, pc);
    SCORE64(sd, xd, pd);
    float nm = fmaxf(m, fmaxf(fmaxf(pa, pb), fmaxf(pc, pd)));
    float sc = __expf(m - nm);
    float ea = __expf(pa - nm), eb = __expf(pb - nm);
    float ec = __expf(pc - nm), ed = __expf(pd - nm);
    l = fmaf(l, sc, (ea + eb) + (ec + ed));
    o = fmaf(o, sc, (ea * xa + eb * xb) + (ec * xc + ed * xd));
    m = nm;
  }
  for (; idx < end; ++idx) {
    int s = edge_src[idx];
    float xv, p;
    SCORE64(s, xv, p);
    float nm = fmaxf(m, p);
    float sc = __expf(m - nm);
    float e  = __expf(p - nm);
    l = fmaf(l, sc, e);
    o = fmaf(o, sc, e * xv);
    m = nm;
  }
#undef SCORE64

  float r = o / l + bias[c];
  // log_softmax across all 64 lanes (= the node's 64 outputs)
  float mx = r;
#pragma unroll
  for (int off = 32; off >= 1; off >>= 1) mx = fmaxf(mx, __shfl_xor(mx, off, 64));
  float ex = __expf(r - mx);
  float se = ex;
#pragma unroll
  for (int off = 32; off >= 1; off >>= 1) se += __shfl_xor(se, off, 64);
  out[(size_t)node * 64 + c] = r - mx - __logf(se);
}

// ---------------- launcher ----------------

extern "C" void kernel_launch(void* const* d_in, const int* in_sizes, int n_in,
                              void* d_out, int out_size, void* d_ws, size_t ws_size,
                              hipStream_t stream) {
  const float* x    = (const float*)d_in[0];
  const int*   ei   = (const int*)d_in[1];
  const float* Wl1  = (const float*)d_in[2];
  const float* Wr1  = (const float*)d_in[3];
  const float* att1 = (const float*)d_in[4];
  const float* b1   = (const float*)d_in[5];
  const float* Wl2  = (const float*)d_in[6];
  const float* Wr2  = (const float*)d_in[7];
  const float* att2 = (const float*)d_in[8];
  const float* b2   = (const float*)d_in[9];
  const float* Wl3  = (const float*)d_in[10];
  const float* Wr3  = (const float*)d_in[11];
  const float* att3 = (const float*)d_in[12];
  const float* b3   = (const float*)d_in[13];
  const int n = in_sizes[0] / DIN;    // 50000
  const int E = in_sizes[1] / 2;      // 800000
  float* out = (float*)d_out;

  float* xl = (float*)d_ws;                      // n*128
  float* xr = xl + (size_t)n * 128;              // n*128
  float* h  = xr + (size_t)n * 128;              // n*128
  int* row_ptr  = (int*)(h + (size_t)n * 128);   // n+1
  int* fill     = row_ptr + (n + 1);             // n (doubles as degree array)
  int* edge_src = fill + n;                      // E+n

  const int tot = E + n;
  const int tb = (tot + 255) / 256;
  hipMemsetAsync(fill, 0, (size_t)n * sizeof(int), stream);
  histo_kernel<<<tb, 256, 0, stream>>>(ei, fill, E, n);
  scan_kernel<<<1, 1024, 0, stream>>>(fill, row_ptr, n);
  hipMemsetAsync(fill, 0, (size_t)n * sizeof(int), stream);
  scatter_kernel<<<tb, 256, 0, stream>>>(ei, row_ptr, fill, edge_src, E, n);

  const int gb = (n + 63) / 64;   // gemm blocks
  const int ab = (n + 3) / 4;     // aggregate blocks (4 waves/block)

  // layer 1
  gemm2_kernel<128><<<gb, 256, 0, stream>>>(x, Wl1, Wr1, xl, xr, n);
  aggregate128_kernel<<<ab, 256, 0, stream>>>(xl, xr, att1, b1, row_ptr, edge_src, h, n);
  // layer 2
  gemm2_kernel<128><<<gb, 256, 0, stream>>>(h, Wl2, Wr2, xl, xr, n);
  aggregate128_kernel<<<ab, 256, 0, stream>>>(xl, xr, att2, b2, row_ptr, edge_src, h, n);
  // layer 3
  gemm2_kernel<64><<<gb, 256, 0, stream>>>(h, Wl3, Wr3, xl, xr, n);
  aggregate64_kernel<<<ab, 256, 0, stream>>>(xl, xr, att3, b3, row_ptr, edge_src, out, n);
}

// Round 3
// 420.955 us; speedup vs baseline: 1.8292x; 1.3937x over previous
//
#include <hip/hip_runtime.h>
#include <math.h>

constexpr int DIN = 128;

typedef __attribute__((ext_vector_type(8))) short short8;
typedef __attribute__((ext_vector_type(4))) float f32x4;

__device__ __forceinline__ unsigned short f2bf(float f) {
  unsigned u = __float_as_uint(f);
  u = (u + 0x7FFF + ((u >> 16) & 1)) >> 16;   // RTN-even
  return (unsigned short)u;
}
__device__ __forceinline__ float bf2f(unsigned short h) {
  return __uint_as_float(((unsigned)h) << 16);
}
__device__ __forceinline__ float bflo(unsigned u) { return __uint_as_float(u << 16); }
__device__ __forceinline__ float bfhi(unsigned u) { return __uint_as_float(u & 0xFFFF0000u); }

typedef const __attribute__((address_space(1))) unsigned int guint_t;
typedef __attribute__((address_space(3))) unsigned int luint_t;
__device__ __forceinline__ void async16(const void* g, void* l) {
  __builtin_amdgcn_global_load_lds((guint_t*)g, (luint_t*)l, 16, 0, 0);
}

// ---------------- CSR build ----------------

__global__ __launch_bounds__(256) void histo_kernel(const int* __restrict__ ei,
                                                    int* __restrict__ deg, int E, int n) {
  int k = blockIdx.x * 256 + threadIdx.x;
  if (k >= E + n) return;
  int dst = (k < E) ? ei[E + k] : (k - E);   // self-loop edges appended
  atomicAdd(&deg[dst], 1);
}

// single-block scan, 4 elems/thread, wave-shfl based
__global__ __launch_bounds__(1024) void scan_kernel(const int* __restrict__ deg,
                                                    int* __restrict__ row_ptr, int n) {
  __shared__ int wsum[16];
  __shared__ int carry;
  const int tid  = threadIdx.x;
  const int lane = tid & 63;
  const int wid  = tid >> 6;
  if (tid == 0) carry = 0;
  __syncthreads();
  for (int base = 0; base < n; base += 4096) {
    int i = base + tid * 4;
    int v0 = 0, v1 = 0, v2 = 0, v3 = 0;
    if (i + 3 < n) { int4 t = *(const int4*)&deg[i]; v0 = t.x; v1 = t.y; v2 = t.z; v3 = t.w; }
    else {
      if (i     < n) v0 = deg[i];
      if (i + 1 < n) v1 = deg[i + 1];
      if (i + 2 < n) v2 = deg[i + 2];
      if (i + 3 < n) v3 = deg[i + 3];
    }
    int s = v0 + v1 + v2 + v3;
    int incl = s;
#pragma unroll
    for (int off = 1; off < 64; off <<= 1) {
      int t = __shfl_up(incl, off, 64);
      if (lane >= off) incl += t;
    }
    if (lane == 63) wsum[wid] = incl;
    __syncthreads();
    if (wid == 0) {
      int wv = (lane < 16) ? wsum[lane] : 0;
#pragma unroll
      for (int off = 1; off < 16; off <<= 1) {
        int t = __shfl_up(wv, off, 64);
        if (lane >= off) wv += t;
      }
      if (lane < 16) wsum[lane] = wv;
    }
    __syncthreads();
    int c     = carry;
    int woff  = (wid == 0) ? 0 : wsum[wid - 1];
    int total = wsum[15];
    __syncthreads();
    int e = c + woff + incl - s;   // exclusive prefix at i
    if (i     < n) row_ptr[i]     = e;
    if (i + 1 < n) row_ptr[i + 1] = e + v0;
    if (i + 2 < n) row_ptr[i + 2] = e + v0 + v1;
    if (i + 3 < n) row_ptr[i + 3] = e + v0 + v1 + v2;
    if (tid == 0) carry = c + total;
    __syncthreads();
  }
  if (tid == 0) row_ptr[n] = carry;
}

__global__ __launch_bounds__(256) void scatter_kernel(const int* __restrict__ ei,
    const int* __restrict__ row_ptr, int* __restrict__ fill,
    int* __restrict__ edge_src, int E, int n) {
  int k = blockIdx.x * 256 + threadIdx.x;
  if (k >= E + n) return;
  int src, dst;
  if (k < E) { src = ei[k]; dst = ei[E + k]; }
  else       { src = k - E; dst = k - E; }
  int pos = row_ptr[dst] + atomicAdd(&fill[dst], 1);
  edge_src[pos] = src;
}

// ---------------- dtype prep ----------------

// x fp32 -> bf16
__global__ __launch_bounds__(256) void cvt_x_kernel(const float* __restrict__ x,
                                                    unsigned short* __restrict__ xb, int total4) {
  int i = blockIdx.x * 256 + threadIdx.x;
  if (i >= total4) return;
  float4 v = *(const float4*)&x[i * 4];
  uint2 o;
  o.x = (unsigned)f2bf(v.x) | ((unsigned)f2bf(v.y) << 16);
  o.y = (unsigned)f2bf(v.z) | ((unsigned)f2bf(v.w) << 16);
  *(uint2*)&xb[i * 4] = o;
}

// all six weights: fp32 [K=128][N] -> bf16 transposed [N][128], packed sequentially
__global__ __launch_bounds__(256) void cvt_w_kernel(
    const float* __restrict__ Wl1, const float* __restrict__ Wr1,
    const float* __restrict__ Wl2, const float* __restrict__ Wr2,
    const float* __restrict__ Wl3, const float* __restrict__ Wr3,
    unsigned short* __restrict__ Wt) {
  int e = blockIdx.x * 256 + threadIdx.x;
  if (e >= 81920) return;
  const float* src; int N; int off;
  if (e < 65536) {
    int m = e >> 14; off = e & 16383; N = 128;
    src = (m == 0) ? Wl1 : (m == 1) ? Wr1 : (m == 2) ? Wl2 : Wr2;
  } else {
    int e2 = e - 65536; int m = e2 >> 13; off = e2 & 8191; N = 64;
    src = m ? Wr3 : Wl3;
  }
  int nn = off >> 7, k = off & 127;          // out[n][k] = in[k][n]
  Wt[e] = f2bf(src[(size_t)k * N + nn]);
}

// ---------------- MFMA dual GEMM: outl = A@Wl, outr = A@Wr (bf16 in, bf16 out, K=128) ----------------
// LDS layout (fragment order): chunk(blk,kk,lane) of 16B at ((blk*4+kk)*64+lane)*16,
// lane = q*16 + r15 holding row (blk*16+r15), k = kk*32+q*8 .. +7.

template<int NC>
__global__ __launch_bounds__(256) void gemm2_mfma(const unsigned short* __restrict__ A,
    const unsigned short* __restrict__ Wlt, const unsigned short* __restrict__ Wrt,
    unsigned short* __restrict__ outl, unsigned short* __restrict__ outr, int M) {
  constexpr int WNB = NC / 16;                   // n-blocks per weight
  __shared__ char lds[16384 + NC * 256];         // A: 16 KB, W: NC*256 B
  char* As = lds;
  char* Ws = lds + 16384;
  const int tid  = threadIdx.x;
  const int w    = tid >> 6, lane = tid & 63;
  const int q    = lane >> 4, r15 = lane & 15;
  const int row0 = blockIdx.x * 64;

  // stage A: wave w handles row block w (16 rows x 128 k)
  {
    int r = row0 + w * 16 + r15; if (r >= M) r = M - 1;
    const char* g = (const char*)A + (size_t)r * 256 + q * 16;
    char* l = As + w * 4096;
#pragma unroll
    for (int kk = 0; kk < 4; ++kk) async16(g + kk * 64, l + kk * 1024);
  }
  // stage Wl
  for (int nt = w; nt < WNB; nt += 4) {
    const char* g = (const char*)Wlt + ((size_t)(nt * 16 + r15)) * 256 + q * 16;
    char* l = Ws + nt * 4096;
#pragma unroll
    for (int kk = 0; kk < 4; ++kk) async16(g + kk * 64, l + kk * 1024);
  }
  __syncthreads();

  const char* aw = As + w * 4096;
  f32x4 acc[WNB] = {};
#pragma unroll
  for (int kk = 0; kk < 4; ++kk) {
    short8 af = *(const short8*)(aw + kk * 1024 + (size_t)lane * 16);
#pragma unroll
    for (int nt = 0; nt < WNB; ++nt) {
      short8 bf = *(const short8*)(Ws + (nt * 4 + kk) * 1024 + (size_t)lane * 16);
      acc[nt] = __builtin_amdgcn_mfma_f32_16x16x32_bf16(af, bf, acc[nt], 0, 0, 0);
    }
  }
  // store pass-1 (C/D: col = lane&15, row = q*4 + reg)
  {
    int rowb = row0 + w * 16 + q * 4;
#pragma unroll
    for (int nt = 0; nt < WNB; ++nt)
#pragma unroll
      for (int r = 0; r < 4; ++r) {
        int rr = rowb + r;
        if (rr < M) outl[(size_t)rr * NC + nt * 16 + r15] = f2bf(acc[nt][r]);
      }
  }
  __syncthreads();   // all ds_reads of Ws done before overwrite
  // stage Wr
  for (int nt = w; nt < WNB; nt += 4) {
    const char* g = (const char*)Wrt + ((size_t)(nt * 16 + r15)) * 256 + q * 16;
    char* l = Ws + nt * 4096;
#pragma unroll
    for (int kk = 0; kk < 4; ++kk) async16(g + kk * 64, l + kk * 1024);
  }
  __syncthreads();

  f32x4 acc2[WNB] = {};
#pragma unroll
  for (int kk = 0; kk < 4; ++kk) {
    short8 af = *(const short8*)(aw + kk * 1024 + (size_t)lane * 16);
#pragma unroll
    for (int nt = 0; nt < WNB; ++nt) {
      short8 bf = *(const short8*)(Ws + (nt * 4 + kk) * 1024 + (size_t)lane * 16);
      acc2[nt] = __builtin_amdgcn_mfma_f32_16x16x32_bf16(af, bf, acc2[nt], 0, 0, 0);
    }
  }
  {
    int rowb = row0 + w * 16 + q * 4;
#pragma unroll
    for (int nt = 0; nt < WNB; ++nt)
#pragma unroll
      for (int r = 0; r < 4; ++r) {
        int rr = rowb + r;
        if (rr < M) outr[(size_t)rr * NC + nt * 16 + r15] = f2bf(acc2[nt][r]);
      }
  }
}

// ---------------- per-node online-softmax aggregation (bf16 in) ----------------
// layers 1-2: 128 ch (4 heads x 32). One wave/node, lane holds ch 2l,2l+1 (same
// head) -> 4-shfl 16-lane head reduce. Edges unrolled x4, combined rescale.

__global__ __launch_bounds__(256) void aggregate128_kernel(
    const unsigned short* __restrict__ xl, const unsigned short* __restrict__ xr,
    const float* __restrict__ att, const float* __restrict__ bias,
    const int* __restrict__ row_ptr, const int* __restrict__ edge_src,
    unsigned short* __restrict__ out, int n) {
  int node = (blockIdx.x * 256 + threadIdx.x) >> 6;
  int lane = threadIdx.x & 63;
  if (node >= n) return;
  const int c = lane * 2;
  unsigned xru = *(const unsigned*)&xr[(size_t)node * 128 + c];
  const float xr0 = bflo(xru), xr1 = bfhi(xru);
  const float2 av = *(const float2*)&att[c];
  float m = -INFINITY, l = 0.f, o0 = 0.f, o1 = 0.f;
  const int beg = row_ptr[node], end = row_ptr[node + 1];
  int idx = beg;

#define SCORE128(S, X0, X1, P)                                    \
  {                                                               \
    unsigned u = *(const unsigned*)&xl[(size_t)(S) * 128 + c];    \
    X0 = bflo(u); X1 = bfhi(u);                                   \
    float t0 = X0 + xr0, t1 = X1 + xr1;                           \
    t0 = t0 > 0.f ? t0 : 0.2f * t0;                               \
    t1 = t1 > 0.f ? t1 : 0.2f * t1;                               \
    P = t0 * av.x + t1 * av.y;                                    \
    P += __shfl_xor(P, 1, 64);                                    \
    P += __shfl_xor(P, 2, 64);                                    \
    P += __shfl_xor(P, 4, 64);                                    \
    P += __shfl_xor(P, 8, 64);                                    \
  }

  for (; idx + 4 <= end; idx += 4) {
    int sa = edge_src[idx], sb = edge_src[idx + 1];
    int sc_ = edge_src[idx + 2], sd = edge_src[idx + 3];
    float xa0, xa1, xb0, xb1, xc0, xc1, xd0, xd1;
    float pa, pb, pc, pd;
    SCORE128(sa, xa0, xa1, pa);
    SCORE128(sb, xb0, xb1, pb);
    SCORE128(sc_, xc0, xc1, pc);
    SCORE128(sd, xd0, xd1, pd);
    float nm = fmaxf(m, fmaxf(fmaxf(pa, pb), fmaxf(pc, pd)));
    float sc = __expf(m - nm);
    float ea = __expf(pa - nm), eb = __expf(pb - nm);
    float ec = __expf(pc - nm), ed = __expf(pd - nm);
    l  = fmaf(l, sc, (ea + eb) + (ec + ed));
    o0 = fmaf(o0, sc, (ea * xa0 + eb * xb0) + (ec * xc0 + ed * xd0));
    o1 = fmaf(o1, sc, (ea * xa1 + eb * xb1) + (ec * xc1 + ed * xd1));
    m = nm;
  }
  for (; idx < end; ++idx) {
    int s = edge_src[idx];
    float x0, x1, p;
    SCORE128(s, x0, x1, p);
    float nm = fmaxf(m, p);
    float sc = __expf(m - nm);
    float e  = __expf(p - nm);
    l  = fmaf(l, sc, e);
    o0 = fmaf(o0, sc, e * x0);
    o1 = fmaf(o1, sc, e * x1);
    m = nm;
  }
#undef SCORE128

  const float2 bv = *(const float2*)&bias[c];
  float r0 = o0 / l + bv.x;
  float r1 = o1 / l + bv.y;
  r0 = r0 > 0.f ? r0 : __expf(r0) - 1.f;   // ELU
  r1 = r1 > 0.f ? r1 : __expf(r1) - 1.f;
  *(unsigned*)&out[(size_t)node * 128 + c] =
      (unsigned)f2bf(r0) | ((unsigned)f2bf(r1) << 16);
}

// layer 3: 64 ch (4 heads x 16), fused log_softmax, fp32 output.

__global__ __launch_bounds__(256) void aggregate64_kernel(
    const unsigned short* __restrict__ xl, const unsigned short* __restrict__ xr,
    const float* __restrict__ att, const float* __restrict__ bias,
    const int* __restrict__ row_ptr, const int* __restrict__ edge_src,
    float* __restrict__ out, int n) {
  int node = (blockIdx.x * 256 + threadIdx.x) >> 6;
  int lane = threadIdx.x & 63;
  if (node >= n) return;
  const int c = lane;                      // head = c/16
  const float xrc = bf2f(xr[(size_t)node * 64 + c]);
  const float a = att[c];
  float m = -INFINITY, l = 0.f, o = 0.f;
  const int beg = row_ptr[node], end = row_ptr[node + 1];
  int idx = beg;

#define SCORE64(S, XV, P)                                         \
  {                                                               \
    XV = bf2f(xl[(size_t)(S) * 64 + c]);                          \
    float t = XV + xrc;                                           \
    t = t > 0.f ? t : 0.2f * t;                                   \
    P = t * a;                                                    \
    P += __shfl_xor(P, 1, 64);                                    \
    P += __shfl_xor(P, 2, 64);                                    \
    P += __shfl_xor(P, 4, 64);                                    \
    P += __shfl_xor(P, 8, 64);                                    \
  }

  for (; idx + 4 <= end; idx += 4) {
    int sa = edge_src[idx], sb = edge_src[idx + 1];
    int sc_ = edge_src[idx + 2], sd = edge_src[idx + 3];
    float xa, xb, xc, xd, pa, pb, pc, pd;
    SCORE64(sa, xa, pa);
    SCORE64(sb, xb, pb);
    SCORE64(sc_, xc, pc);
    SCORE64(sd, xd, pd);
    float nm = fmaxf(m, fmaxf(fmaxf(pa, pb), fmaxf(pc, pd)));
    float sc = __expf(m - nm);
    float ea = __expf(pa - nm), eb = __expf(pb - nm);
    float ec = __expf(pc - nm), ed = __expf(pd - nm);
    l = fmaf(l, sc, (ea + eb) + (ec + ed));
    o = fmaf(o, sc, (ea * xa + eb * xb) + (ec * xc + ed * xd));
    m = nm;
  }
  for (; idx < end; ++idx) {
    int s = edge_src[idx];
    float xv, p;
    SCORE64(s, xv, p);
    float nm = fmaxf(m, p);
    float sc = __expf(m - nm);
    float e  = __expf(p - nm);
    l = fmaf(l, sc, e);
    o = fmaf(o, sc, e * xv);
    m = nm;
  }
#undef SCORE64

  float r = o / l + bias[c];
  // log_softmax across all 64 lanes
  float mx = r;
#pragma unroll
  for (int off = 32; off >= 1; off >>= 1) mx = fmaxf(mx, __shfl_xor(mx, off, 64));
  float ex = __expf(r - mx);
  float se = ex;
#pragma unroll
  for (int off = 32; off >= 1; off >>= 1) se += __shfl_xor(se, off, 64);
  out[(size_t)node * 64 + c] = r - mx - __logf(se);
}

// ---------------- launcher ----------------

extern "C" void kernel_launch(void* const* d_in, const int* in_sizes, int n_in,
                              void* d_out, int out_size, void* d_ws, size_t ws_size,
                              hipStream_t stream) {
  const float* x    = (const float*)d_in[0];
  const int*   ei   = (const int*)d_in[1];
  const float* Wl1  = (const float*)d_in[2];
  const float* Wr1  = (const float*)d_in[3];
  const float* att1 = (const float*)d_in[4];
  const float* b1   = (const float*)d_in[5];
  const float* Wl2  = (const float*)d_in[6];
  const float* Wr2  = (const float*)d_in[7];
  const float* att2 = (const float*)d_in[8];
  const float* b2   = (const float*)d_in[9];
  const float* Wl3  = (const float*)d_in[10];
  const float* Wr3  = (const float*)d_in[11];
  const float* att3 = (const float*)d_in[12];
  const float* b3   = (const float*)d_in[13];
  const int n = in_sizes[0] / DIN;    // 50000
  const int E = in_sizes[1] / 2;      // 800000
  float* out = (float*)d_out;

  unsigned short* xb = (unsigned short*)d_ws;     // n*128 bf16
  unsigned short* xl = xb + (size_t)n * 128;      // n*128
  unsigned short* xr = xl + (size_t)n * 128;      // n*128
  unsigned short* h  = xr + (size_t)n * 128;      // n*128
  unsigned short* Wt = h + (size_t)n * 128;       // 81920 bf16 (transposed weights)
  unsigned short* Wl1t = Wt, *Wr1t = Wt + 16384;
  unsigned short* Wl2t = Wt + 32768, *Wr2t = Wt + 49152;
  unsigned short* Wl3t = Wt + 65536, *Wr3t = Wt + 73728;
  int* row_ptr  = (int*)(Wt + 81920);             // n+1 (padded to n+16 for alignment)
  int* fill     = row_ptr + (n + 16);             // n (doubles as degree array)
  int* edge_src = fill + n;                       // E+n

  // ---- prep: weight transpose+cvt, x cvt
  cvt_w_kernel<<<320, 256, 0, stream>>>(Wl1, Wr1, Wl2, Wr2, Wl3, Wr3, Wt);
  cvt_x_kernel<<<(n * 128 / 4 + 255) / 256, 256, 0, stream>>>(x, xb, n * 128 / 4);

  // ---- CSR build
  const int tot = E + n;
  const int tb = (tot + 255) / 256;
  hipMemsetAsync(fill, 0, (size_t)n * sizeof(int), stream);
  histo_kernel<<<tb, 256, 0, stream>>>(ei, fill, E, n);
  scan_kernel<<<1, 1024, 0, stream>>>(fill, row_ptr, n);
  hipMemsetAsync(fill, 0, (size_t)n * sizeof(int), stream);
  scatter_kernel<<<tb, 256, 0, stream>>>(ei, row_ptr, fill, edge_src, E, n);

  const int gb = (n + 63) / 64;   // gemm blocks
  const int ab = (n + 3) / 4;     // aggregate blocks (4 waves/block)

  // layer 1
  gemm2_mfma<128><<<gb, 256, 0, stream>>>(xb, Wl1t, Wr1t, xl, xr, n);
  aggregate128_kernel<<<ab, 256, 0, stream>>>(xl, xr, att1, b1, row_ptr, edge_src, h, n);
  // layer 2
  gemm2_mfma<128><<<gb, 256, 0, stream>>>(h, Wl2t, Wr2t, xl, xr, n);
  aggregate128_kernel<<<ab, 256, 0, stream>>>(xl, xr, att2, b2, row_ptr, edge_src, h, n);
  // layer 3
  gemm2_mfma<64><<<gb, 256, 0, stream>>>(h, Wl3t, Wr3t, xl, xr, n);
  aggregate64_kernel<<<ab, 256, 0, stream>>>(xl, xr, att3, b3, row_ptr, edge_src, out, n);
}

// Round 4
// 361.780 us; speedup vs baseline: 2.1284x; 1.1636x over previous
//
#include <hip/hip_runtime.h>
#include <math.h>

constexpr int DIN = 128;

typedef __attribute__((ext_vector_type(8))) short short8;
typedef __attribute__((ext_vector_type(4))) float f32x4;

__device__ __forceinline__ unsigned short f2bf(float f) {
  unsigned u = __float_as_uint(f);
  u = (u + 0x7FFF + ((u >> 16) & 1)) >> 16;   // RTN-even
  return (unsigned short)u;
}
__device__ __forceinline__ float bf2f(unsigned short h) {
  return __uint_as_float(((unsigned)h) << 16);
}
__device__ __forceinline__ float bflo(unsigned u) { return __uint_as_float(u << 16); }
__device__ __forceinline__ float bfhi(unsigned u) { return __uint_as_float(u & 0xFFFF0000u); }

__device__ __forceinline__ void unpack8(uint4 u, float* x) {
  x[0] = bflo(u.x); x[1] = bfhi(u.x); x[2] = bflo(u.y); x[3] = bfhi(u.y);
  x[4] = bflo(u.z); x[5] = bfhi(u.z); x[6] = bflo(u.w); x[7] = bfhi(u.w);
}
__device__ __forceinline__ void unpack4(uint2 u, float* x) {
  x[0] = bflo(u.x); x[1] = bfhi(u.x); x[2] = bflo(u.y); x[3] = bfhi(u.y);
}

typedef const __attribute__((address_space(1))) unsigned int guint_t;
typedef __attribute__((address_space(3))) unsigned int luint_t;
__device__ __forceinline__ void async16(const void* g, void* l) {
  __builtin_amdgcn_global_load_lds((guint_t*)g, (luint_t*)l, 16, 0, 0);
}

// ---------------- CSR build ----------------

__global__ __launch_bounds__(256) void histo_kernel(const int* __restrict__ ei,
                                                    int* __restrict__ deg, int E, int n) {
  int k = blockIdx.x * 256 + threadIdx.x;
  if (k >= E + n) return;
  int dst = (k < E) ? ei[E + k] : (k - E);   // self-loop edges appended
  atomicAdd(&deg[dst], 1);
}

// single-block scan, 4 elems/thread, wave-shfl based. Also zeroes deg (fill).
__global__ __launch_bounds__(1024) void scan_kernel(int* __restrict__ deg,
                                                    int* __restrict__ row_ptr, int n) {
  __shared__ int wsum[16];
  __shared__ int carry;
  const int tid  = threadIdx.x;
  const int lane = tid & 63;
  const int wid  = tid >> 6;
  if (tid == 0) carry = 0;
  __syncthreads();
  for (int base = 0; base < n; base += 4096) {
    int i = base + tid * 4;
    int v0 = 0, v1 = 0, v2 = 0, v3 = 0;
    if (i + 3 < n) {
      int4 t = *(const int4*)&deg[i]; v0 = t.x; v1 = t.y; v2 = t.z; v3 = t.w;
      *(int4*)&deg[i] = make_int4(0, 0, 0, 0);
    } else {
      if (i     < n) { v0 = deg[i];     deg[i]     = 0; }
      if (i + 1 < n) { v1 = deg[i + 1]; deg[i + 1] = 0; }
      if (i + 2 < n) { v2 = deg[i + 2]; deg[i + 2] = 0; }
      if (i + 3 < n) { v3 = deg[i + 3]; deg[i + 3] = 0; }
    }
    int s = v0 + v1 + v2 + v3;
    int incl = s;
#pragma unroll
    for (int off = 1; off < 64; off <<= 1) {
      int t = __shfl_up(incl, off, 64);
      if (lane >= off) incl += t;
    }
    if (lane == 63) wsum[wid] = incl;
    __syncthreads();
    if (wid == 0) {
      int wv = (lane < 16) ? wsum[lane] : 0;
#pragma unroll
      for (int off = 1; off < 16; off <<= 1) {
        int t = __shfl_up(wv, off, 64);
        if (lane >= off) wv += t;
      }
      if (lane < 16) wsum[lane] = wv;
    }
    __syncthreads();
    int c     = carry;
    int woff  = (wid == 0) ? 0 : wsum[wid - 1];
    int total = wsum[15];
    __syncthreads();
    int e = c + woff + incl - s;   // exclusive prefix at i
    if (i     < n) row_ptr[i]     = e;
    if (i + 1 < n) row_ptr[i + 1] = e + v0;
    if (i + 2 < n) row_ptr[i + 2] = e + v0 + v1;
    if (i + 3 < n) row_ptr[i + 3] = e + v0 + v1 + v2;
    if (tid == 0) carry = c + total;
    __syncthreads();
  }
  if (tid == 0) row_ptr[n] = carry;
}

__global__ __launch_bounds__(256) void scatter_kernel(const int* __restrict__ ei,
    const int* __restrict__ row_ptr, int* __restrict__ fill,
    int* __restrict__ edge_src, int E, int n) {
  int k = blockIdx.x * 256 + threadIdx.x;
  if (k >= E + n) return;
  int src, dst;
  if (k < E) { src = ei[k]; dst = ei[E + k]; }
  else       { src = k - E; dst = k - E; }
  int pos = row_ptr[dst] + atomicAdd(&fill[dst], 1);
  edge_src[pos] = src;
}

// ---------------- dtype prep ----------------

__global__ __launch_bounds__(256) void cvt_x_kernel(const float* __restrict__ x,
                                                    unsigned short* __restrict__ xb, int total4) {
  int i = blockIdx.x * 256 + threadIdx.x;
  if (i >= total4) return;
  float4 v = *(const float4*)&x[i * 4];
  uint2 o;
  o.x = (unsigned)f2bf(v.x) | ((unsigned)f2bf(v.y) << 16);
  o.y = (unsigned)f2bf(v.z) | ((unsigned)f2bf(v.w) << 16);
  *(uint2*)&xb[i * 4] = o;
}

// all six weights: fp32 [K=128][N] -> bf16 transposed [N][128], packed sequentially
__global__ __launch_bounds__(256) void cvt_w_kernel(
    const float* __restrict__ Wl1, const float* __restrict__ Wr1,
    const float* __restrict__ Wl2, const float* __restrict__ Wr2,
    const float* __restrict__ Wl3, const float* __restrict__ Wr3,
    unsigned short* __restrict__ Wt) {
  int e = blockIdx.x * 256 + threadIdx.x;
  if (e >= 81920) return;
  const float* src; int N; int off;
  if (e < 65536) {
    int m = e >> 14; off = e & 16383; N = 128;
    src = (m == 0) ? Wl1 : (m == 1) ? Wr1 : (m == 2) ? Wl2 : Wr2;
  } else {
    int e2 = e - 65536; int m = e2 >> 13; off = e2 & 8191; N = 64;
    src = m ? Wr3 : Wl3;
  }
  int nn = off >> 7, k = off & 127;          // out[n][k] = in[k][n]
  Wt[e] = f2bf(src[(size_t)k * N + nn]);
}

// ---------------- MFMA dual GEMM: outl = A@Wl, outr = A@Wr (bf16, K=128) ----------------
// LDS layout (fragment order): chunk(blk,kk,lane) of 16B at ((blk*4+kk)*64+lane)*16,
// lane = q*16 + r15 holding row (blk*16+r15), k = kk*32+q*8 .. +7.

template<int NC>
__global__ __launch_bounds__(256) void gemm2_mfma(const unsigned short* __restrict__ A,
    const unsigned short* __restrict__ Wlt, const unsigned short* __restrict__ Wrt,
    unsigned short* __restrict__ outl, unsigned short* __restrict__ outr, int M) {
  constexpr int WNB = NC / 16;                   // n-blocks per weight
  __shared__ char lds[16384 + NC * 256];         // A: 16 KB, W: NC*256 B
  char* As = lds;
  char* Ws = lds + 16384;
  const int tid  = threadIdx.x;
  const int w    = tid >> 6, lane = tid & 63;
  const int q    = lane >> 4, r15 = lane & 15;
  const int row0 = blockIdx.x * 64;

  // stage A: wave w handles row block w (16 rows x 128 k)
  {
    int r = row0 + w * 16 + r15; if (r >= M) r = M - 1;
    const char* g = (const char*)A + (size_t)r * 256 + q * 16;
    char* l = As + w * 4096;
#pragma unroll
    for (int kk = 0; kk < 4; ++kk) async16(g + kk * 64, l + kk * 1024);
  }
  // stage Wl
  for (int nt = w; nt < WNB; nt += 4) {
    const char* g = (const char*)Wlt + ((size_t)(nt * 16 + r15)) * 256 + q * 16;
    char* l = Ws + nt * 4096;
#pragma unroll
    for (int kk = 0; kk < 4; ++kk) async16(g + kk * 64, l + kk * 1024);
  }
  __syncthreads();

  const char* aw = As + w * 4096;
  f32x4 acc[WNB] = {};
#pragma unroll
  for (int kk = 0; kk < 4; ++kk) {
    short8 af = *(const short8*)(aw + kk * 1024 + (size_t)lane * 16);
#pragma unroll
    for (int nt = 0; nt < WNB; ++nt) {
      short8 bf = *(const short8*)(Ws + (nt * 4 + kk) * 1024 + (size_t)lane * 16);
      acc[nt] = __builtin_amdgcn_mfma_f32_16x16x32_bf16(af, bf, acc[nt], 0, 0, 0);
    }
  }
  // store pass-1 (C/D: col = lane&15, row = q*4 + reg)
  {
    int rowb = row0 + w * 16 + q * 4;
#pragma unroll
    for (int nt = 0; nt < WNB; ++nt)
#pragma unroll
      for (int r = 0; r < 4; ++r) {
        int rr = rowb + r;
        if (rr < M) outl[(size_t)rr * NC + nt * 16 + r15] = f2bf(acc[nt][r]);
      }
  }
  __syncthreads();   // all ds_reads of Ws done before overwrite
  // stage Wr
  for (int nt = w; nt < WNB; nt += 4) {
    const char* g = (const char*)Wrt + ((size_t)(nt * 16 + r15)) * 256 + q * 16;
    char* l = Ws + nt * 4096;
#pragma unroll
    for (int kk = 0; kk < 4; ++kk) async16(g + kk * 64, l + kk * 1024);
  }
  __syncthreads();

  f32x4 acc2[WNB] = {};
#pragma unroll
  for (int kk = 0; kk < 4; ++kk) {
    short8 af = *(const short8*)(aw + kk * 1024 + (size_t)lane * 16);
#pragma unroll
    for (int nt = 0; nt < WNB; ++nt) {
      short8 bf = *(const short8*)(Ws + (nt * 4 + kk) * 1024 + (size_t)lane * 16);
      acc2[nt] = __builtin_amdgcn_mfma_f32_16x16x32_bf16(af, bf, acc2[nt], 0, 0, 0);
    }
  }
  {
    int rowb = row0 + w * 16 + q * 4;
#pragma unroll
    for (int nt = 0; nt < WNB; ++nt)
#pragma unroll
      for (int r = 0; r < 4; ++r) {
        int rr = rowb + r;
        if (rr < M) outr[(size_t)rr * NC + nt * 16 + r15] = f2bf(acc2[nt][r]);
      }
  }
}

// ---------------- aggregation: 4 nodes/wave, 16 lanes/node ----------------
// layers 1-2: 128 ch. Lane r (0..15) of a group holds ch r*8..r*8+7; head = 32 ch
// = 4 lanes -> 2-shfl score reduce. No-max softmax: scores are O(10) << 88 so
// exp cannot overflow (clamped at 80 for safety); identical math to the
// max-subtracted reference softmax.

__global__ __launch_bounds__(256) void aggregate128_kernel(
    const unsigned short* __restrict__ xl, const unsigned short* __restrict__ xr,
    const float* __restrict__ att, const float* __restrict__ bias,
    const int* __restrict__ row_ptr, const int* __restrict__ edge_src,
    unsigned short* __restrict__ out, int n) {
  const int tid  = threadIdx.x;
  const int r    = tid & 15;
  const int node = blockIdx.x * 16 + (tid >> 4);
  if (node >= n) return;
  const int c0 = r * 8;

  float xrv[8];
  unpack8(*(const uint4*)&xr[(size_t)node * 128 + c0], xrv);
  float a6[8], a4[8];
  {
    float4 aa = *(const float4*)&att[c0];
    float4 ab = *(const float4*)&att[c0 + 4];
    float at[8] = {aa.x, aa.y, aa.z, aa.w, ab.x, ab.y, ab.z, ab.w};
#pragma unroll
    for (int j = 0; j < 8; ++j) { a6[j] = 0.6f * at[j]; a4[j] = 0.4f * at[j]; }
  }

  float l = 0.f, o[8] = {};
  int idx = row_ptr[node];
  const int end = row_ptr[node + 1];

  for (; idx + 2 <= end; idx += 2) {
    int s0 = edge_src[idx], s1 = edge_src[idx + 1];
    uint4 u0 = *(const uint4*)&xl[(size_t)s0 * 128 + c0];
    uint4 u1 = *(const uint4*)&xl[(size_t)s1 * 128 + c0];
    float x0[8], x1[8];
    unpack8(u0, x0); unpack8(u1, x1);
    float p0 = 0.f, p1 = 0.f;
#pragma unroll
    for (int j = 0; j < 8; ++j) {
      float t = x0[j] + xrv[j];
      p0 = fmaf(t, a6[j], p0); p0 = fmaf(fabsf(t), a4[j], p0);
    }
#pragma unroll
    for (int j = 0; j < 8; ++j) {
      float t = x1[j] + xrv[j];
      p1 = fmaf(t, a6[j], p1); p1 = fmaf(fabsf(t), a4[j], p1);
    }
    p0 += __shfl_xor(p0, 1, 64); p0 += __shfl_xor(p0, 2, 64);
    p1 += __shfl_xor(p1, 1, 64); p1 += __shfl_xor(p1, 2, 64);
    float e0 = __expf(fminf(p0, 80.f));
    float e1 = __expf(fminf(p1, 80.f));
    l += e0 + e1;
#pragma unroll
    for (int j = 0; j < 8; ++j) o[j] = fmaf(e0, x0[j], fmaf(e1, x1[j], o[j]));
  }
  if (idx < end) {
    int s0 = edge_src[idx];
    uint4 u0 = *(const uint4*)&xl[(size_t)s0 * 128 + c0];
    float x0[8];
    unpack8(u0, x0);
    float p0 = 0.f;
#pragma unroll
    for (int j = 0; j < 8; ++j) {
      float t = x0[j] + xrv[j];
      p0 = fmaf(t, a6[j], p0); p0 = fmaf(fabsf(t), a4[j], p0);
    }
    p0 += __shfl_xor(p0, 1, 64); p0 += __shfl_xor(p0, 2, 64);
    float e0 = __expf(fminf(p0, 80.f));
    l += e0;
#pragma unroll
    for (int j = 0; j < 8; ++j) o[j] = fmaf(e0, x0[j], o[j]);
  }

  float4 b0 = *(const float4*)&bias[c0];
  float4 b1 = *(const float4*)&bias[c0 + 4];
  float bb[8] = {b0.x, b0.y, b0.z, b0.w, b1.x, b1.y, b1.z, b1.w};
  unsigned short res[8];
#pragma unroll
  for (int j = 0; j < 8; ++j) {
    float v = o[j] / l + bb[j];
    v = v > 0.f ? v : __expf(v) - 1.f;   // ELU
    res[j] = f2bf(v);
  }
  uint4 ov;
  ov.x = (unsigned)res[0] | ((unsigned)res[1] << 16);
  ov.y = (unsigned)res[2] | ((unsigned)res[3] << 16);
  ov.z = (unsigned)res[4] | ((unsigned)res[5] << 16);
  ov.w = (unsigned)res[6] | ((unsigned)res[7] << 16);
  *(uint4*)&out[(size_t)node * 128 + c0] = ov;
}

// layer 3: 64 ch, 4 nodes/wave, 16 lanes/node, 4 ch/lane; head = 16 ch = 4 lanes.
// Fused log_softmax over the node's 64 outputs (16-lane reduce), fp32 out.

__global__ __launch_bounds__(256) void aggregate64_kernel(
    const unsigned short* __restrict__ xl, const unsigned short* __restrict__ xr,
    const float* __restrict__ att, const float* __restrict__ bias,
    const int* __restrict__ row_ptr, const int* __restrict__ edge_src,
    float* __restrict__ out, int n) {
  const int tid  = threadIdx.x;
  const int r    = tid & 15;
  const int node = blockIdx.x * 16 + (tid >> 4);
  if (node >= n) return;
  const int c0 = r * 4;

  float xrv[4];
  unpack4(*(const uint2*)&xr[(size_t)node * 64 + c0], xrv);
  float a6[4], a4[4];
  {
    float4 aa = *(const float4*)&att[c0];
    float at[4] = {aa.x, aa.y, aa.z, aa.w};
#pragma unroll
    for (int j = 0; j < 4; ++j) { a6[j] = 0.6f * at[j]; a4[j] = 0.4f * at[j]; }
  }

  float l = 0.f, o[4] = {};
  int idx = row_ptr[node];
  const int end = row_ptr[node + 1];

  for (; idx + 2 <= end; idx += 2) {
    int s0 = edge_src[idx], s1 = edge_src[idx + 1];
    uint2 u0 = *(const uint2*)&xl[(size_t)s0 * 64 + c0];
    uint2 u1 = *(const uint2*)&xl[(size_t)s1 * 64 + c0];
    float x0[4], x1[4];
    unpack4(u0, x0); unpack4(u1, x1);
    float p0 = 0.f, p1 = 0.f;
#pragma unroll
    for (int j = 0; j < 4; ++j) {
      float t = x0[j] + xrv[j];
      p0 = fmaf(t, a6[j], p0); p0 = fmaf(fabsf(t), a4[j], p0);
    }
#pragma unroll
    for (int j = 0; j < 4; ++j) {
      float t = x1[j] + xrv[j];
      p1 = fmaf(t, a6[j], p1); p1 = fmaf(fabsf(t), a4[j], p1);
    }
    p0 += __shfl_xor(p0, 1, 64); p0 += __shfl_xor(p0, 2, 64);
    p1 += __shfl_xor(p1, 1, 64); p1 += __shfl_xor(p1, 2, 64);
    float e0 = __expf(fminf(p0, 80.f));
    float e1 = __expf(fminf(p1, 80.f));
    l += e0 + e1;
#pragma unroll
    for (int j = 0; j < 4; ++j) o[j] = fmaf(e0, x0[j], fmaf(e1, x1[j], o[j]));
  }
  if (idx < end) {
    int s0 = edge_src[idx];
    uint2 u0 = *(const uint2*)&xl[(size_t)s0 * 64 + c0];
    float x0[4];
    unpack4(u0, x0);
    float p0 = 0.f;
#pragma unroll
    for (int j = 0; j < 4; ++j) {
      float t = x0[j] + xrv[j];
      p0 = fmaf(t, a6[j], p0); p0 = fmaf(fabsf(t), a4[j], p0);
    }
    p0 += __shfl_xor(p0, 1, 64); p0 += __shfl_xor(p0, 2, 64);
    float e0 = __expf(fminf(p0, 80.f));
    l += e0;
#pragma unroll
    for (int j = 0; j < 4; ++j) o[j] = fmaf(e0, x0[j], o[j]);
  }

  float4 bv = *(const float4*)&bias[c0];
  float bb[4] = {bv.x, bv.y, bv.z, bv.w};
  float rr[4];
#pragma unroll
  for (int j = 0; j < 4; ++j) rr[j] = o[j] / l + bb[j];

  // log_softmax over the node's 64 outputs (16-lane group)
  float mx = fmaxf(fmaxf(rr[0], rr[1]), fmaxf(rr[2], rr[3]));
#pragma unroll
  for (int off = 1; off < 16; off <<= 1) mx = fmaxf(mx, __shfl_xor(mx, off, 64));
  float se = __expf(rr[0] - mx) + __expf(rr[1] - mx) +
             __expf(rr[2] - mx) + __expf(rr[3] - mx);
#pragma unroll
  for (int off = 1; off < 16; off <<= 1) se += __shfl_xor(se, off, 64);
  float ls = mx + __logf(se);
  *(float4*)&out[(size_t)node * 64 + c0] =
      make_float4(rr[0] - ls, rr[1] - ls, rr[2] - ls, rr[3] - ls);
}

// ---------------- launcher ----------------

extern "C" void kernel_launch(void* const* d_in, const int* in_sizes, int n_in,
                              void* d_out, int out_size, void* d_ws, size_t ws_size,
                              hipStream_t stream) {
  const float* x    = (const float*)d_in[0];
  const int*   ei   = (const int*)d_in[1];
  const float* Wl1  = (const float*)d_in[2];
  const float* Wr1  = (const float*)d_in[3];
  const float* att1 = (const float*)d_in[4];
  const float* b1   = (const float*)d_in[5];
  const float* Wl2  = (const float*)d_in[6];
  const float* Wr2  = (const float*)d_in[7];
  const float* att2 = (const float*)d_in[8];
  const float* b2   = (const float*)d_in[9];
  const float* Wl3  = (const float*)d_in[10];
  const float* Wr3  = (const float*)d_in[11];
  const float* att3 = (const float*)d_in[12];
  const float* b3   = (const float*)d_in[13];
  const int n = in_sizes[0] / DIN;    // 50000
  const int E = in_sizes[1] / 2;      // 800000
  float* out = (float*)d_out;

  unsigned short* xb = (unsigned short*)d_ws;     // n*128 bf16
  unsigned short* xl = xb + (size_t)n * 128;      // n*128
  unsigned short* xr = xl + (size_t)n * 128;      // n*128
  unsigned short* h  = xr + (size_t)n * 128;      // n*128
  unsigned short* Wt = h + (size_t)n * 128;       // 81920 bf16 (transposed weights)
  unsigned short* Wl1t = Wt, *Wr1t = Wt + 16384;
  unsigned short* Wl2t = Wt + 32768, *Wr2t = Wt + 49152;
  unsigned short* Wl3t = Wt + 65536, *Wr3t = Wt + 73728;
  int* row_ptr  = (int*)(Wt + 81920);             // n+1 (padded)
  int* fill     = row_ptr + (n + 16);             // n (doubles as degree array)
  int* edge_src = fill + n;                       // E+n

  // ---- prep: weight transpose+cvt, x cvt
  cvt_w_kernel<<<320, 256, 0, stream>>>(Wl1, Wr1, Wl2, Wr2, Wl3, Wr3, Wt);
  cvt_x_kernel<<<(n * 128 / 4 + 255) / 256, 256, 0, stream>>>(x, xb, n * 128 / 4);

  // ---- CSR build
  const int tot = E + n;
  const int tb = (tot + 255) / 256;
  hipMemsetAsync(fill, 0, (size_t)n * sizeof(int), stream);
  histo_kernel<<<tb, 256, 0, stream>>>(ei, fill, E, n);
  scan_kernel<<<1, 1024, 0, stream>>>(fill, row_ptr, n);   // also zeroes fill
  scatter_kernel<<<tb, 256, 0, stream>>>(ei, row_ptr, fill, edge_src, E, n);

  const int gb = (n + 63) / 64;   // gemm blocks
  const int ab = (n + 15) / 16;   // aggregate blocks (16 nodes/block)

  // layer 1
  gemm2_mfma<128><<<gb, 256, 0, stream>>>(xb, Wl1t, Wr1t, xl, xr, n);
  aggregate128_kernel<<<ab, 256, 0, stream>>>(xl, xr, att1, b1, row_ptr, edge_src, h, n);
  // layer 2
  gemm2_mfma<128><<<gb, 256, 0, stream>>>(h, Wl2t, Wr2t, xl, xr, n);
  aggregate128_kernel<<<ab, 256, 0, stream>>>(xl, xr, att2, b2, row_ptr, edge_src, h, n);
  // layer 3
  gemm2_mfma<64><<<gb, 256, 0, stream>>>(h, Wl3t, Wr3t, xl, xr, n);
  aggregate64_kernel<<<ab, 256, 0, stream>>>(xl, xr, att3, b3, row_ptr, edge_src, out, n);
}